// Round 11
// baseline (123.544 us; speedup 1.0000x reference)
//
#include <hip/hip_runtime.h>
#include <hip/hip_bf16.h>

// CovPooling: B=4096 graphs, n=512 nodes/graph, D=64 features.
// cov = X^T X / n - mu mu^T, upper triangle packed (2080 per graph).
// R11: R8's validated config (aux=2 NT reads, PLAIN stores — NT stores were
//      R9/R10's -4us) + persistent blocks: each block streams 4 contiguous
//      graphs through one never-draining DMA pipeline (global chunk counter
//      across graph boundaries; per-graph epilogue overlaps next graph's
//      in-flight DMA). Kills 3/4 of pipeline fills and all mid-grid drains.

#define DD   64
#define NPG  512
#define NCH  16     // chunks of 32 nodes per graph
#define GPB  4      // graphs per block

typedef __bf16 bf16x8 __attribute__((ext_vector_type(8)));
typedef float  f32x4  __attribute__((ext_vector_type(4)));

typedef __attribute__((address_space(3))) void       lds_void;
typedef const __attribute__((address_space(1))) void gbl_void;

#define MFMA(a, b, c) __builtin_amdgcn_mfma_f32_16x16x32_bf16((a), (b), (c), 0, 0, 0)
#define AUX_NT 2    // CPol: NT (non-temporal) — R8-validated

__global__ __launch_bounds__(256, 4)
void cov_pool_kernel(const float* __restrict__ X, float* __restrict__ out,
                     int n_graphs) {
  // 4 chunk buffers: [buf][node 0..31][dim-slot 0..63] f32 (8 KB each)
  __shared__ __align__(16) float sh[4][2048];
  __shared__ float muv[DD];

  const int tid  = threadIdx.x;
  const int lane = tid & 63;
  const int w    = tid >> 6;          // wave 0..3
  const int q    = lane & 15;
  const int grp  = lane >> 4;         // node group 0..3 (8 nodes each)
  const long g0  = (long)blockIdx.x * GPB;
  const int ngr  = (n_graphs - g0 < GPB) ? (int)(n_graphs - g0) : GPB;
  const int T    = ngr * NCH;         // total chunks this block streams

  // DMA source for this lane, chunk 0, quad nq=2w (nodes 8w..8w+3):
  // node = 2w*4 + grp, fetched dim-quad = q ^ 2w  (XOR pre-swizzle so that
  // LDS slot d' holds X[dim d' ^ 8w]; reads un-permute below).
  const float* srcA = X + g0 * (NPG * DD)
                    + (size_t)((2 * w) * 4 + grp) * DD + 4 * (q ^ (2 * w));

  // fragment read base slots (floats within one chunk buffer):
  // X[node 8*grp + j][dim 16*t + q]  ->  slot grp*512 + 64*j + ((16t|q) ^ 8*grp)
  const int vb0 = grp * 512 + (( 0 | q) ^ (8 * grp));
  const int vb1 = grp * 512 + ((16 | q) ^ (8 * grp));
  const int vb2 = grp * 512 + ((32 | q) ^ (8 * grp));
  const int vb3 = grp * 512 + ((48 | q) ^ (8 * grp));

  bf16x8 ones;
  #pragma unroll
  for (int j = 0; j < 8; ++j) ones[j] = (__bf16)1.0f;

  auto stage = [&](int cc) {          // issue 2 KB of NT DMA for global chunk cc
    const float* s = srcA + (size_t)cc * (32 * DD);
    float* d = &sh[cc & 3][(2 * w) * 256];
    __builtin_amdgcn_global_load_lds((gbl_void*)s,         (lds_void*)d,         16, 0, AUX_NT);
    __builtin_amdgcn_global_load_lds((gbl_void*)(s + 256), (lds_void*)(d + 256), 16, 0, AUX_NT);
  };

  stage(0); stage(1); stage(2);       // fill once per BLOCK, not per graph

  const float inv_n = 1.f / NPG;
  int cc = 0;
  #pragma unroll 1
  for (int gi = 0; gi < ngr; ++gi) {
    f32x4 z = {0.f, 0.f, 0.f, 0.f};
    f32x4 a00=z,a01=z,a02=z,a03=z,a11=z,a12=z,a13=z,a22=z,a23=z,a33=z;
    f32x4 am0=z,am1=z,am2=z,am3=z;    // ones^T X (wave 3 only)

    #pragma unroll
    for (int c = 0; c < NCH; ++c, ++cc) {
      // my prev LDS reads retired; chunk-cc DMA landed; all waves agree
      asm volatile("s_waitcnt lgkmcnt(0)" ::: "memory");
      if (cc < T - 2)       asm volatile("s_waitcnt vmcnt(4)" ::: "memory");
      else if (cc == T - 2) asm volatile("s_waitcnt vmcnt(2)" ::: "memory");
      else                  asm volatile("s_waitcnt vmcnt(0)" ::: "memory");
      __builtin_amdgcn_s_barrier();
      asm volatile("" ::: "memory");

      if (cc + 3 < T) stage(cc + 3);  // overwrites buf (cc-1)&3 — safe post-barrier

      const float* buf = sh[cc & 3];
      bf16x8 b0, b1, b2, b3;
      #pragma unroll
      for (int j = 0; j < 8; ++j) {
        b0[j] = (__bf16)buf[vb0 + 64 * j];
        b1[j] = (__bf16)buf[vb1 + 64 * j];
        b2[j] = (__bf16)buf[vb2 + 64 * j];
        b3[j] = (__bf16)buf[vb3 + 64 * j];
      }
      if (w == 0)      { a00 = MFMA(b0, b0, a00); a01 = MFMA(b0, b1, a01); a02 = MFMA(b0, b2, a02); }
      else if (w == 1) { a03 = MFMA(b0, b3, a03); a11 = MFMA(b1, b1, a11); a12 = MFMA(b1, b2, a12); }
      else if (w == 2) { a13 = MFMA(b1, b3, a13); a22 = MFMA(b2, b2, a22); a23 = MFMA(b2, b3, a23); }
      else             { a33 = MFMA(b3, b3, a33);
                         am0 = MFMA(ones, b0, am0); am1 = MFMA(ones, b1, am1);
                         am2 = MFMA(ones, b2, am2); am3 = MFMA(ones, b3, am3); }
    }

    // ---- per-graph epilogue (next graph's DMA already in flight) ----
    if (w == 3 && lane < 16) {
      muv[ 0 + lane] = am0[0] * inv_n;
      muv[16 + lane] = am1[0] * inv_n;
      muv[32 + lane] = am2[0] * inv_n;
      muv[48 + lane] = am3[0] * inv_n;
    }
    asm volatile("s_waitcnt lgkmcnt(0)" ::: "memory");
    __builtin_amdgcn_s_barrier();
    asm volatile("" ::: "memory");

    float* og = out + (g0 + gi) * 2080L;
    const int rl4 = grp * 4;          // C row base within 16-tile
    auto wtile = [&](int tr, int tc, const f32x4& A, bool diag) {
      const int j = tc * 16 + q;
      const float mcj = muv[j];
      #pragma unroll
      for (int r = 0; r < 4; ++r) {
        const int i = tr * 16 + rl4 + r;
        if (!diag || j >= i)
          og[i * DD - (i * (i - 1)) / 2 + (j - i)] = A[r] * inv_n - muv[i] * mcj;
      }
    };
    if (w == 0)      { wtile(0, 0, a00, true);  wtile(0, 1, a01, false); wtile(0, 2, a02, false); }
    else if (w == 1) { wtile(0, 3, a03, false); wtile(1, 1, a11, true);  wtile(1, 2, a12, false); }
    else if (w == 2) { wtile(1, 3, a13, false); wtile(2, 2, a22, true);  wtile(2, 3, a23, false); }
    else             { wtile(3, 3, a33, true); }
    // muv is re-written only after 16 more barriers (next epilogue) — safe.
  }
}

extern "C" void kernel_launch(void* const* d_in, const int* in_sizes, int n_in,
                              void* d_out, int out_size, void* d_ws, size_t ws_size,
                              hipStream_t stream) {
  const float* X = (const float*)d_in[0];
  float* out = (float*)d_out;
  const int N = in_sizes[0] / DD;     // total nodes
  const int B = N / NPG;              // graphs
  cov_pool_kernel<<<dim3((B + GPB - 1) / GPB), dim3(256), 0, stream>>>(X, out, B);
}

// Round 12
// 106.241 us; speedup vs baseline: 1.1629x; 1.1629x over previous
//
#include <hip/hip_runtime.h>
#include <hip/hip_bf16.h>

// CovPooling: B=4096 graphs, n=512 nodes/graph, D=64 features.
// cov = X^T X / n - mu mu^T, upper triangle packed (2080 per graph).
// R12: exact revert to R8 (the measured best, 106.9 us):
//      1 block = 1 graph; global_load_lds DMA (16B, aux=2 NT) into 4-deep
//      LDS chunk buffers; counted vmcnt (never drains mid-stream) + one raw
//      barrier per iter; XOR-swizzled storage via pre-swizzled global source
//      (conflict-free f32 fragment reads); cvt->bf16 in-register; MFMA tiles
//      split across 4 waves; mean via ones-MFMA on wave 3; PLAIN stores
//      (NT stores cost +4us in R9/R10; persistence cost +17us in R11).

#define DD   64
#define NPG  512
#define NCH  16     // chunks of 32 nodes

typedef __bf16 bf16x8 __attribute__((ext_vector_type(8)));
typedef float  f32x4  __attribute__((ext_vector_type(4)));

typedef __attribute__((address_space(3))) void       lds_void;
typedef const __attribute__((address_space(1))) void gbl_void;

#define MFMA(a, b, c) __builtin_amdgcn_mfma_f32_16x16x32_bf16((a), (b), (c), 0, 0, 0)
#define AUX_NT 2    // CPol: NT (non-temporal) — the R8-validated winner

__global__ __launch_bounds__(256, 4)
void cov_pool_kernel(const float* __restrict__ X, float* __restrict__ out) {
  // 4 chunk buffers: [buf][node 0..31][dim-slot 0..63] f32 (8 KB each)
  __shared__ __align__(16) float sh[4][2048];
  __shared__ float muv[DD];

  const int tid  = threadIdx.x;
  const int lane = tid & 63;
  const int w    = tid >> 6;          // wave 0..3
  const int q    = lane & 15;
  const int grp  = lane >> 4;         // node group 0..3 (8 nodes each)
  const long g   = blockIdx.x;
  const float* Xg = X + g * (long)(NPG * DD);

  // DMA source for this lane, chunk 0, quad nq=2w (nodes 8w..8w+3):
  // node = 2w*4 + grp, fetched dim-quad = q ^ 2w  (XOR pre-swizzle so that
  // LDS slot d' holds X[dim d' ^ 8w]; reads un-permute below).
  const float* srcA = Xg + (size_t)((2 * w) * 4 + grp) * DD + 4 * (q ^ (2 * w));

  // fragment read base slots (floats within one chunk buffer):
  // X[node 8*grp + j][dim 16*t + q]  ->  slot grp*512 + 64*j + ((16t|q) ^ 8*grp)
  const int vb0 = grp * 512 + (( 0 | q) ^ (8 * grp));
  const int vb1 = grp * 512 + ((16 | q) ^ (8 * grp));
  const int vb2 = grp * 512 + ((32 | q) ^ (8 * grp));
  const int vb3 = grp * 512 + ((48 | q) ^ (8 * grp));

  f32x4 z = {0.f, 0.f, 0.f, 0.f};
  f32x4 a00=z,a01=z,a02=z,a03=z,a11=z,a12=z,a13=z,a22=z,a23=z,a33=z;
  f32x4 am0=z,am1=z,am2=z,am3=z;      // ones^T X (wave 3 only)

  bf16x8 ones;
  #pragma unroll
  for (int j = 0; j < 8; ++j) ones[j] = (__bf16)1.0f;

  auto stage = [&](int c) {           // issue 2 KB of NT DMA for chunk c
    const float* s = srcA + (size_t)c * (32 * DD);
    float* d = &sh[c & 3][(2 * w) * 256];
    __builtin_amdgcn_global_load_lds((gbl_void*)s,         (lds_void*)d,         16, 0, AUX_NT);
    __builtin_amdgcn_global_load_lds((gbl_void*)(s + 256), (lds_void*)(d + 256), 16, 0, AUX_NT);
  };

  stage(0); stage(1); stage(2);       // prologue: 3 chunks in flight

  #pragma unroll
  for (int c = 0; c < NCH; ++c) {
    // my prev-iter LDS reads retired; my chunk-c DMA landed; all waves agree
    asm volatile("s_waitcnt lgkmcnt(0)" ::: "memory");
    if (c < NCH - 2)       asm volatile("s_waitcnt vmcnt(4)" ::: "memory");
    else if (c == NCH - 2) asm volatile("s_waitcnt vmcnt(2)" ::: "memory");
    else                   asm volatile("s_waitcnt vmcnt(0)" ::: "memory");
    __builtin_amdgcn_s_barrier();
    asm volatile("" ::: "memory");

    if (c + 3 < NCH) stage(c + 3);    // overwrites buf (c-1)&3 — safe post-barrier

    const float* buf = sh[c & 3];
    bf16x8 b0, b1, b2, b3;
    #pragma unroll
    for (int j = 0; j < 8; ++j) {
      b0[j] = (__bf16)buf[vb0 + 64 * j];
      b1[j] = (__bf16)buf[vb1 + 64 * j];
      b2[j] = (__bf16)buf[vb2 + 64 * j];
      b3[j] = (__bf16)buf[vb3 + 64 * j];
    }
    if (w == 0)      { a00 = MFMA(b0, b0, a00); a01 = MFMA(b0, b1, a01); a02 = MFMA(b0, b2, a02); }
    else if (w == 1) { a03 = MFMA(b0, b3, a03); a11 = MFMA(b1, b1, a11); a12 = MFMA(b1, b2, a12); }
    else if (w == 2) { a13 = MFMA(b1, b3, a13); a22 = MFMA(b2, b2, a22); a23 = MFMA(b2, b3, a23); }
    else             { a33 = MFMA(b3, b3, a33);
                       am0 = MFMA(ones, b0, am0); am1 = MFMA(ones, b1, am1);
                       am2 = MFMA(ones, b2, am2); am3 = MFMA(ones, b3, am3); }
  }

  // ---- wave 3 publishes mu (every lane's am_t[0] = colsum(16t + q)) ----
  if (w == 3 && lane < 16) {
    const float inv_n = 1.f / NPG;
    muv[ 0 + lane] = am0[0] * inv_n;
    muv[16 + lane] = am1[0] * inv_n;
    muv[32 + lane] = am2[0] * inv_n;
    muv[48 + lane] = am3[0] * inv_n;
  }
  asm volatile("s_waitcnt lgkmcnt(0)" ::: "memory");
  __builtin_amdgcn_s_barrier();
  asm volatile("" ::: "memory");

  // ---- epilogue: cov = acc/n - mu_i mu_j, packed upper triangle ----
  const float inv_n = 1.f / NPG;
  float* og = out + g * 2080L;
  const int rl4 = grp * 4;            // C row base within 16-tile
  auto wtile = [&](int tr, int tc, const f32x4& A, bool diag) {
    const int j = tc * 16 + q;
    const float mcj = muv[j];
    #pragma unroll
    for (int r = 0; r < 4; ++r) {
      const int i = tr * 16 + rl4 + r;
      if (!diag || j >= i)
        og[i * DD - (i * (i - 1)) / 2 + (j - i)] = A[r] * inv_n - muv[i] * mcj;
    }
  };
  if (w == 0)      { wtile(0, 0, a00, true);  wtile(0, 1, a01, false); wtile(0, 2, a02, false); }
  else if (w == 1) { wtile(0, 3, a03, false); wtile(1, 1, a11, true);  wtile(1, 2, a12, false); }
  else if (w == 2) { wtile(1, 3, a13, false); wtile(2, 2, a22, true);  wtile(2, 3, a23, false); }
  else             { wtile(3, 3, a33, true); }
}

extern "C" void kernel_launch(void* const* d_in, const int* in_sizes, int n_in,
                              void* d_out, int out_size, void* d_ws, size_t ws_size,
                              hipStream_t stream) {
  const float* X = (const float*)d_in[0];
  float* out = (float*)d_out;
  const int N = in_sizes[0] / DD;     // total nodes
  const int B = N / NPG;              // graphs
  cov_pool_kernel<<<dim3(B), dim3(256), 0, stream>>>(X, out);
}